// Round 6
// baseline (264.301 us; speedup 1.0000x reference)
//
#include <hip/hip_runtime.h>

// SegmentationAugmentation: fused affine-grid + trilinear grid_sample (border,
// align_corners=False) for input (float out) and label (bool-as-float out).
//
// R9: R8 post-mortem — bytes are minimal (FETCH 127.5MB = unique footprint,
// WRITE 134MB = output) and compute needs only ~13us of issue, yet the kernel
// sits at ~65us vs the 41.5us byte-floor: every wave serially eats its own
// gather latency (issue 4 DMA -> stall -> ~250cyc compute -> exit), and all
// resident waves share that profile. R9 pipelines across columns:
//  1) persistent waves: each wave owns 32 CONTIGUOUS columns (4096 waves,
//     512 blocks = 2 blocks/CU co-resident; 66KB LDS/block). Consecutive
//     columns shift the gather base by <=1 row -> most DMAs L2-hit, and
//     per-wave store streams are sequential.
//  2) 2-deep double-buffered pipeline, wave-local, no barriers: DMAs for
//     col c+1 fly into buf[(c+1)&1] while col c computes from buf[c&1].
//     Counted waits (never drain-to-0): steady vmcnt(6) = {4 next-col DMAs
//     + 2 prev-col stores} outstanding; prologue vmcnt(4); tail vmcnt(2).
//     Counts are reorder-robust: every vmem op is pinned between asm
//     volatile memory barriers and the per-window op-set is fixed.
//  3) z-path hoisted out of the column loop (depends only on lane).
// Carried over: one wave per column-slice, paired-z (lane does z=2l,2l+1),
// global_load_lds DMA staging, nt stores, in/lab guard layout.
//
// Keeps the R4-R8-validated z-edge elimination: read s[iz0], s[iz0+1]
// directly; at iz0==127 fz==+0 so z1-plane weights are +0 and the one-past
// value (next row's z0 or a zeroed guard) contributes +-0 — bit-identical
// to the reference's +0*s[127] (absmax 0.0 across R4-R8).
//
// CORRECTNESS-CRITICAL: label output is a hard comparator (acc > 0.5) with
// voxels ~0.5 ulp from the boundary; all float math must stay bit-exact vs
// numpy: contract(off), x/y/z paths verbatim, w = (wz*wy)*wx, reference
// corner accumulation order (z outer, y mid, x inner). Restructuring only
// changes where/when identical bits flow.

#define NV 128
#define TOTAL (8 * NV * NV * NV)
#define WPB 8                 // waves per block
#define WSTRIDE 1032          // floats per buffer: in 0..511, guard 512,
                              // lab 516..1027, guard 1028 (+pad, 16B-aligned)
#define CHUNK 32              // contiguous columns per wave
#define NBLK (TOTAL / NV / WPB / CHUNK)   // 512 blocks = 2/CU co-resident

typedef float v2f __attribute__((ext_vector_type(2)));

__global__ __launch_bounds__(512, 4) void seg_aug_kernel(
    const float* __restrict__ in,
    const float* __restrict__ lab,
    const float* __restrict__ T,   // 16 floats, 4x4 row-major; rows 0..2 used
    float* __restrict__ out_in,
    float* __restrict__ out_lab)
{
#pragma clang fp contract(off)
    __shared__ __align__(16) float s[WPB * 2 * WSTRIDE];   // 66048 B

    const int t = threadIdx.x;
    const int l = t & 63;                                   // lane
    const int w = __builtin_amdgcn_readfirstlane(t >> 6);   // wave id (uniform)
    const int gw = blockIdx.x * WPB + w;                    // global wave
    const int col0 = gw * CHUNK;                            // first column
    const int b = col0 >> 14;                               // constant per chunk
    const size_t bbase = (size_t)b << 21;                   // b * 128^3
    const float* ibp = in  + bbase;
    const float* lbp = lab + bbase;
    float* sw0 = &s[w * 2 * WSTRIDE];
    float* sw1 = sw0 + WSTRIDE;
    if (l == 0) { sw0[512] = 0.0f; sw0[1028] = 0.0f;        // finite one-past
                  sw1[512] = 0.0f; sw1[1028] = 0.0f; }      // guards, both bufs

    // uniform transform entries (s_loads), same bits as direct T[i] use
    const float T0 = T[0], T1 = T[1], T3v = T[3];
    const float T4 = T[4], T5 = T[5], T7v = T[7];
    const float T10 = T[10], T11 = T[11];

    // ---- per-lane z path, column-independent -> hoisted (verbatim R3) ----
    float p4a = (2.0f * (float)(2 * l) + 1.0f) / 128.0f - 1.0f;
    float uza = T10 * p4a + T11;
    float gza = ((uza + 1.0f) * 128.0f - 1.0f) * 0.5f;
    gza = fminf(fmaxf(gza, 0.0f), 127.0f);
    float fz0a = floorf(gza);
    const int   iza = (int)fz0a;
    const float fza = gza - fz0a;
    float p4b = (2.0f * (float)(2 * l + 1) + 1.0f) / 128.0f - 1.0f;
    float uzb = T10 * p4b + T11;
    float gzb = ((uzb + 1.0f) * 128.0f - 1.0f) * 0.5f;
    gzb = fminf(fmaxf(gzb, 0.0f), 127.0f);
    float fz0b = floorf(gzb);
    const int   izb = (int)fz0b;
    const float fzb = gzb - fz0b;
    const float awz0 = 1.0f - fza, awz1 = fza;
    const float bwz0 = 1.0f - fzb, bwz1 = fzb;

    const int segoff = (l & 31) * 4;
    const bool loA = (l < 32);

    // STAGE: xy path (verbatim R3) for COL, issue 4 DMAs into SW, export fx/fy
    #define STAGE(COL, SW, FXV, FYV)                                          \
    {                                                                         \
        const int o3 = (COL) & (NV - 1);                                      \
        const int o2 = ((COL) >> 7) & (NV - 1);                               \
        float p2 = (2.0f * (float)o2 + 1.0f) / 128.0f - 1.0f;                 \
        float p3 = (2.0f * (float)o3 + 1.0f) / 128.0f - 1.0f;                 \
        float ux = (T0 * p2 + T1 * p3) + T3v;                                 \
        float uy = (T4 * p2 + T5 * p3) + T7v;                                 \
        float gx = ((ux + 1.0f) * 128.0f - 1.0f) * 0.5f;                      \
        float gy = ((uy + 1.0f) * 128.0f - 1.0f) * 0.5f;                      \
        gx = fminf(fmaxf(gx, 0.0f), 127.0f);                                  \
        gy = fminf(fmaxf(gy, 0.0f), 127.0f);                                  \
        float fx0f = floorf(gx), fy0f = floorf(gy);                           \
        FXV = gx - fx0f;                                                      \
        FYV = gy - fy0f;                                                      \
        const int ix0 = __builtin_amdgcn_readfirstlane((int)fx0f);            \
        const int iy0 = __builtin_amdgcn_readfirstlane((int)fy0f);            \
        const int ix1 = min(ix0 + 1, NV - 1);                                 \
        const int iy1 = min(iy0 + 1, NV - 1);                                 \
        const int r00 = (ix0 * NV + iy0) * NV;                                \
        const int r01 = (ix0 * NV + iy1) * NV;                                \
        const int r10 = (ix1 * NV + iy0) * NV;                                \
        const int r11 = (ix1 * NV + iy1) * NV;                                \
        const int offA = (loA ? r00 : r01) + segoff;                          \
        const int offB = (loA ? r10 : r11) + segoff;                          \
        __builtin_amdgcn_global_load_lds(ibp + offA, (SW),       16, 0, 0);   \
        __builtin_amdgcn_global_load_lds(ibp + offB, (SW) + 256, 16, 0, 0);   \
        __builtin_amdgcn_global_load_lds(lbp + offA, (SW) + 516, 16, 0, 0);   \
        __builtin_amdgcn_global_load_lds(lbp + offB, (SW) + 772, 16, 0, 0);   \
    }

    // COMPUTE: weights from (fx,fy,z-path), 32 LDS reads, accumulate (verbatim
    // R8 order), 2 nt stores for COL
    #define COMPUTE(COL, SW, FXV, FYV)                                        \
    {                                                                         \
        const float wx0 = 1.0f - (FXV), wx1 = (FXV);                          \
        const float wy0 = 1.0f - (FYV), wy1 = (FYV);                          \
        float atz0y0 = awz0 * wy0, atz0y1 = awz0 * wy1;                       \
        float atz1y0 = awz1 * wy0, atz1y1 = awz1 * wy1;                       \
        float aw1 = atz0y0 * wx0, aw2 = atz0y0 * wx1;                         \
        float aw3 = atz0y1 * wx0, aw4 = atz0y1 * wx1;                         \
        float aw5 = atz1y0 * wx0, aw6 = atz1y0 * wx1;                         \
        float aw7 = atz1y1 * wx0, aw8 = atz1y1 * wx1;                         \
        float btz0y0 = bwz0 * wy0, btz0y1 = bwz0 * wy1;                       \
        float btz1y0 = bwz1 * wy0, btz1y1 = bwz1 * wy1;                       \
        float bw1 = btz0y0 * wx0, bw2 = btz0y0 * wx1;                         \
        float bw3 = btz0y1 * wx0, bw4 = btz0y1 * wx1;                         \
        float bw5 = btz1y0 * wx0, bw6 = btz1y0 * wx1;                         \
        float bw7 = btz1y1 * wx0, bw8 = btz1y1 * wx1;                         \
        const int obase = (COL) * NV;                                         \
        {                                                                     \
            const float* rpa = (SW) + iza;                                    \
            float a00 = rpa[0*NV], a00p = rpa[0*NV+1];                        \
            float a01 = rpa[1*NV], a01p = rpa[1*NV+1];                        \
            float a10 = rpa[2*NV], a10p = rpa[2*NV+1];                        \
            float a11 = rpa[3*NV], a11p = rpa[3*NV+1];                        \
            float acc_a = 0.0f;                                               \
            acc_a = acc_a + a00  * aw1;                                       \
            acc_a = acc_a + a10  * aw2;                                       \
            acc_a = acc_a + a01  * aw3;                                       \
            acc_a = acc_a + a11  * aw4;                                       \
            acc_a = acc_a + a00p * aw5;                                       \
            acc_a = acc_a + a10p * aw6;                                       \
            acc_a = acc_a + a01p * aw7;                                       \
            acc_a = acc_a + a11p * aw8;                                       \
            const float* rpb = (SW) + izb;                                    \
            float c00 = rpb[0*NV], c00p = rpb[0*NV+1];                        \
            float c01 = rpb[1*NV], c01p = rpb[1*NV+1];                        \
            float c10 = rpb[2*NV], c10p = rpb[2*NV+1];                        \
            float c11 = rpb[3*NV], c11p = rpb[3*NV+1];                        \
            float acc_b = 0.0f;                                               \
            acc_b = acc_b + c00  * bw1;                                       \
            acc_b = acc_b + c10  * bw2;                                       \
            acc_b = acc_b + c01  * bw3;                                       \
            acc_b = acc_b + c11  * bw4;                                       \
            acc_b = acc_b + c00p * bw5;                                       \
            acc_b = acc_b + c10p * bw6;                                       \
            acc_b = acc_b + c01p * bw7;                                       \
            acc_b = acc_b + c11p * bw8;                                       \
            v2f v; v.x = acc_a; v.y = acc_b;                                  \
            __builtin_nontemporal_store(v, (v2f*)(out_in + obase) + l);       \
        }                                                                     \
        {                                                                     \
            const float* lpa = (SW) + 516 + iza;                              \
            float a00 = lpa[0*NV], a00p = lpa[0*NV+1];                        \
            float a01 = lpa[1*NV], a01p = lpa[1*NV+1];                        \
            float a10 = lpa[2*NV], a10p = lpa[2*NV+1];                        \
            float a11 = lpa[3*NV], a11p = lpa[3*NV+1];                        \
            float acc_a = 0.0f;                                               \
            acc_a = acc_a + a00  * aw1;                                       \
            acc_a = acc_a + a10  * aw2;                                       \
            acc_a = acc_a + a01  * aw3;                                       \
            acc_a = acc_a + a11  * aw4;                                       \
            acc_a = acc_a + a00p * aw5;                                       \
            acc_a = acc_a + a10p * aw6;                                       \
            acc_a = acc_a + a01p * aw7;                                       \
            acc_a = acc_a + a11p * aw8;                                       \
            const float* lpb = (SW) + 516 + izb;                              \
            float c00 = lpb[0*NV], c00p = lpb[0*NV+1];                        \
            float c01 = lpb[1*NV], c01p = lpb[1*NV+1];                        \
            float c10 = lpb[2*NV], c10p = lpb[2*NV+1];                        \
            float c11 = lpb[3*NV], c11p = lpb[3*NV+1];                        \
            float acc_b = 0.0f;                                               \
            acc_b = acc_b + c00  * bw1;                                       \
            acc_b = acc_b + c10  * bw2;                                       \
            acc_b = acc_b + c01  * bw3;                                       \
            acc_b = acc_b + c11  * bw4;                                       \
            acc_b = acc_b + c00p * bw5;                                       \
            acc_b = acc_b + c10p * bw6;                                       \
            acc_b = acc_b + c01p * bw7;                                       \
            acc_b = acc_b + c11p * bw8;                                       \
            v2f v;                                                            \
            v.x = (acc_a > 0.5f) ? 1.0f : 0.0f;                               \
            v.y = (acc_b > 0.5f) ? 1.0f : 0.0f;                               \
            __builtin_nontemporal_store(v, (v2f*)(out_lab + obase) + l);      \
        }                                                                     \
    }

    float fxc, fyc, fxn, fyn;
    float* cur = sw0;
    float* nxt = sw1;

    // prologue: fill the pipe
    STAGE(col0, cur, fxc, fyc);

    // k = 0: only DMA(c0) is older than this window's 4 new DMAs
    STAGE(col0 + 1, nxt, fxn, fyn);
    asm volatile("s_waitcnt vmcnt(4)" ::: "memory");
    __builtin_amdgcn_sched_barrier(0);
    COMPUTE(col0, cur, fxc, fyc);
    fxc = fxn; fyc = fyn;
    { float* tmp = cur; cur = nxt; nxt = tmp; }

    // steady state: outstanding allowed = 4 next-col DMAs + 2 prev-col stores
#pragma clang loop unroll(disable)
    for (int k = 1; k <= CHUNK - 2; ++k) {
        STAGE(col0 + k + 1, nxt, fxn, fyn);
        asm volatile("s_waitcnt vmcnt(6)" ::: "memory");
        __builtin_amdgcn_sched_barrier(0);
        COMPUTE(col0 + k, cur, fxc, fyc);
        fxc = fxn; fyc = fyn;
        { float* tmp = cur; cur = nxt; nxt = tmp; }
    }

    // tail: only the 2 stores of col CHUNK-2 are newer than our DMAs
    asm volatile("s_waitcnt vmcnt(2)" ::: "memory");
    __builtin_amdgcn_sched_barrier(0);
    COMPUTE(col0 + CHUNK - 1, cur, fxc, fyc);

    #undef STAGE
    #undef COMPUTE
}

extern "C" void kernel_launch(void* const* d_in, const int* in_sizes, int n_in,
                              void* d_out, int out_size, void* d_ws, size_t ws_size,
                              hipStream_t stream) {
    const float* in  = (const float*)d_in[0];
    const float* lab = (const float*)d_in[1];
    const float* T   = (const float*)d_in[2];
    float* out_in  = (float*)d_out;
    float* out_lab = (float*)d_out + TOTAL;

    // persistent-ish: 512 blocks (2/CU), each wave pipelines 32 contiguous cols
    seg_aug_kernel<<<dim3(NBLK), dim3(512), 0, stream>>>(
        in, lab, T, out_in, out_lab);
}

// Round 7
// 247.190 us; speedup vs baseline: 1.0692x; 1.0692x over previous
//
#include <hip/hip_runtime.h>

// SegmentationAugmentation: fused affine-grid + trilinear grid_sample (border,
// align_corners=False) for input (float out) and label (bool-as-float out).
//
// R10: R9 post-mortem — LDS double-buffering halved occupancy (66KB -> 2
// blocks/CU = 16 waves/CU, Occupancy 78->35%) and regressed to 101us; TLP at
// 32 waves/CU was the real latency-hider. R8 (65us) is the right structure.
// R10 = R8 + bijective XCD-chunked block swizzle (T1): consecutive R8 blocks
// share most input rows (gy drifts ~1px/column) but round-robin across the 8
// XCDs, duplicating the row band into multiple per-XCD L2s (L3 absorbs it —
// FETCH stays ~unique — but every DMA pays L3/HBM latency and the fabric
// carries the duplicate fills). Remap vbid = (bid&7)*(NWG/8) + (bid>>3)
// (NWG=16384, %8==0 -> bijective): each XCD owns 16384 contiguous columns =
// one batch b = a 16.8MB slice streamed once, with the active ~130-row band
// (~133KB) L2-resident. No instruction-stream change.
//
// Carried from R8 (absmax 0.0 validated): one independent wave per column,
// no barriers; paired-z (lane does z=2l,2l+1); global_load_lds DMA staging;
// split-vmcnt {inA,inB} / vmcnt(2) / {labA,labB} / vmcnt(1); nt stores;
// in-kernel xy/z math (verbatim R0-R4 expressions); 33KB LDS, 52 VGPR ->
// 4 blocks/CU = 32 waves/CU.
//
// Keeps the R4-R9-validated z-edge elimination: read s[iz0], s[iz0+1]
// directly; at iz0==127 fz==+0 so z1-plane weights are +0 and the one-past
// value (next row's z0 or a zeroed guard) contributes +-0 — bit-identical
// to the reference's +0*s[127] (absmax 0.0 across R4-R9).
//
// CORRECTNESS-CRITICAL: label output is a hard comparator (acc > 0.5) with
// voxels ~0.5 ulp from the boundary; all float math must stay bit-exact vs
// numpy: contract(off), x/y/z paths verbatim, w = (wz*wy)*wx, reference
// corner accumulation order (z outer, y mid, x inner). The swizzle only
// permutes which block computes which column.

#define NV 128
#define TOTAL (8 * NV * NV * NV)
#define WPB 8                 // waves (= columns) per block
#define NWG (TOTAL / NV / WPB)   // 16384 workgroups
#define WSTRIDE 1032          // floats per wave region: in 0..511, guard 512,
                              // lab 516..1027, guard 1028 (+pad, 16B-aligned)

typedef float v2f __attribute__((ext_vector_type(2)));

__global__ __launch_bounds__(512) void seg_aug_kernel(
    const float* __restrict__ in,
    const float* __restrict__ lab,
    const float* __restrict__ T,   // 16 floats, 4x4 row-major; rows 0..2 used
    float* __restrict__ out_in,
    float* __restrict__ out_lab)
{
#pragma clang fp contract(off)
    __shared__ __align__(16) float s[WPB * WSTRIDE];

    const int t = threadIdx.x;
    const int l = t & 63;                                   // lane
    const int w = __builtin_amdgcn_readfirstlane(t >> 6);   // wave id (uniform)

    // XCD-chunked bijective swizzle: HW assigns block i to XCD i%8; give each
    // XCD a CONTIGUOUS 2048-block (16384-column = one batch) range so the
    // drifting row band stays in that XCD's L2.
    const int vb = ((blockIdx.x & 7) << 11) | (blockIdx.x >> 3);
    const int col = (vb << 3) | w;                          // global column
    const int o3 = col & (NV - 1);
    const int o2 = (col >> 7) & (NV - 1);
    const int b  = col >> 14;

    // ---- column-uniform x/y path (verbatim R3; T[i] are uniform s_loads) ----
    float p2 = (2.0f * (float)o2 + 1.0f) / 128.0f - 1.0f;
    float p3 = (2.0f * (float)o3 + 1.0f) / 128.0f - 1.0f;
    float ux = (T[0] * p2 + T[1] * p3) + T[3];
    float uy = (T[4] * p2 + T[5] * p3) + T[7];
    float gx = ((ux + 1.0f) * 128.0f - 1.0f) * 0.5f;
    float gy = ((uy + 1.0f) * 128.0f - 1.0f) * 0.5f;
    gx = fminf(fmaxf(gx, 0.0f), 127.0f);
    gy = fminf(fmaxf(gy, 0.0f), 127.0f);
    float fx0f = floorf(gx), fy0f = floorf(gy);
    float fx = gx - fx0f;
    float fy = gy - fy0f;
    const int ix0 = __builtin_amdgcn_readfirstlane((int)fx0f);
    const int iy0 = __builtin_amdgcn_readfirstlane((int)fy0f);
    const int ix1 = min(ix0 + 1, NV - 1);
    const int iy1 = min(iy0 + 1, NV - 1);
    const int r00 = (ix0 * NV + iy0) * NV;
    const int r01 = (ix0 * NV + iy1) * NV;
    const int r10 = (ix1 * NV + iy0) * NV;
    const int r11 = (ix1 * NV + iy1) * NV;

    // per-lane DMA sources: inst A = rows {00,01}, inst B = rows {10,11}
    // (when iy unclamped these are contiguous 1KB bursts)
    const int segoff = (l & 31) * 4;
    const int offA = ((l < 32) ? r00 : r01) + segoff;
    const int offB = ((l < 32) ? r10 : r11) + segoff;
    const size_t bbase = (size_t)b << 21;    // b * 128^3
    const float* ibp = in  + bbase;
    const float* lbp = lab + bbase;
    float* sw = &s[w * WSTRIDE];

    // ---- group 1 (oldest vmem ops): input DMAs ----
    __builtin_amdgcn_global_load_lds(ibp + offA, sw,       16, 0, 0);
    __builtin_amdgcn_global_load_lds(ibp + offB, sw + 256, 16, 0, 0);
    __builtin_amdgcn_sched_barrier(0);       // pin group order for vmcnt counting
    // ---- group 2: label DMAs ----
    __builtin_amdgcn_global_load_lds(lbp + offA, sw + 516, 16, 0, 0);
    __builtin_amdgcn_global_load_lds(lbp + offB, sw + 772, 16, 0, 0);

    if (l == 0) { sw[512] = 0.0f; sw[1028] = 0.0f; }   // finite one-past guards

    // ---- per-lane z path for z = 2l and 2l+1 (verbatim R3; overlaps DMA) ----
    float p4a = (2.0f * (float)(2 * l) + 1.0f) / 128.0f - 1.0f;
    float uza = T[10] * p4a + T[11];
    float gza = ((uza + 1.0f) * 128.0f - 1.0f) * 0.5f;
    gza = fminf(fmaxf(gza, 0.0f), 127.0f);
    float fz0a = floorf(gza);
    const int   iza = (int)fz0a;
    const float fza = gza - fz0a;

    float p4b = (2.0f * (float)(2 * l + 1) + 1.0f) / 128.0f - 1.0f;
    float uzb = T[10] * p4b + T[11];
    float gzb = ((uzb + 1.0f) * 128.0f - 1.0f) * 0.5f;
    gzb = fminf(fmaxf(gzb, 0.0f), 127.0f);
    float fz0b = floorf(gzb);
    const int   izb = (int)fz0b;
    const float fzb = gzb - fz0b;

    // ---- weights (VALU overlaps DMA latency) ----
    const float wx0 = 1.0f - fx, wx1 = fx;
    const float wy0 = 1.0f - fy, wy1 = fy;

    const float awz0 = 1.0f - fza, awz1 = fza;
    float atz0y0 = awz0 * wy0, atz0y1 = awz0 * wy1;
    float atz1y0 = awz1 * wy0, atz1y1 = awz1 * wy1;
    float aw1 = atz0y0 * wx0, aw2 = atz0y0 * wx1;
    float aw3 = atz0y1 * wx0, aw4 = atz0y1 * wx1;
    float aw5 = atz1y0 * wx0, aw6 = atz1y0 * wx1;
    float aw7 = atz1y1 * wx0, aw8 = atz1y1 * wx1;

    const float bwz0 = 1.0f - fzb, bwz1 = fzb;
    float btz0y0 = bwz0 * wy0, btz0y1 = bwz0 * wy1;
    float btz1y0 = bwz1 * wy0, btz1y1 = bwz1 * wy1;
    float bw1 = btz0y0 * wx0, bw2 = btz0y0 * wx1;
    float bw3 = btz0y1 * wx0, bw4 = btz0y1 * wx1;
    float bw5 = btz1y0 * wx0, bw6 = btz1y0 * wx1;
    float bw7 = btz1y1 * wx0, bw8 = btz1y1 * wx1;

    const int obase = col * NV;

    // ==== input half: needs only {inA, inB} -> vmcnt(2) ====
    asm volatile("s_waitcnt vmcnt(2)" ::: "memory");
    __builtin_amdgcn_sched_barrier(0);
    {
        const float* rpa = sw + iza;
        float a00 = rpa[0*NV], a00p = rpa[0*NV+1];
        float a01 = rpa[1*NV], a01p = rpa[1*NV+1];
        float a10 = rpa[2*NV], a10p = rpa[2*NV+1];
        float a11 = rpa[3*NV], a11p = rpa[3*NV+1];
        float acc_a = 0.0f;
        acc_a = acc_a + a00  * aw1;
        acc_a = acc_a + a10  * aw2;
        acc_a = acc_a + a01  * aw3;
        acc_a = acc_a + a11  * aw4;
        acc_a = acc_a + a00p * aw5;
        acc_a = acc_a + a10p * aw6;
        acc_a = acc_a + a01p * aw7;
        acc_a = acc_a + a11p * aw8;

        const float* rpb = sw + izb;
        float c00 = rpb[0*NV], c00p = rpb[0*NV+1];
        float c01 = rpb[1*NV], c01p = rpb[1*NV+1];
        float c10 = rpb[2*NV], c10p = rpb[2*NV+1];
        float c11 = rpb[3*NV], c11p = rpb[3*NV+1];
        float acc_b = 0.0f;
        acc_b = acc_b + c00  * bw1;
        acc_b = acc_b + c10  * bw2;
        acc_b = acc_b + c01  * bw3;
        acc_b = acc_b + c11  * bw4;
        acc_b = acc_b + c00p * bw5;
        acc_b = acc_b + c10p * bw6;
        acc_b = acc_b + c01p * bw7;
        acc_b = acc_b + c11p * bw8;

        v2f v; v.x = acc_a; v.y = acc_b;
        __builtin_nontemporal_store(v, (v2f*)(out_in + obase) + l);
    }

    // ==== label half: labs are the oldest remaining; the in-store is the
    // one allowed outstanding op -> vmcnt(1) ====
    asm volatile("s_waitcnt vmcnt(1)" ::: "memory");
    __builtin_amdgcn_sched_barrier(0);
    {
        const float* lpa = sw + 516 + iza;
        float a00 = lpa[0*NV], a00p = lpa[0*NV+1];
        float a01 = lpa[1*NV], a01p = lpa[1*NV+1];
        float a10 = lpa[2*NV], a10p = lpa[2*NV+1];
        float a11 = lpa[3*NV], a11p = lpa[3*NV+1];
        float acc_a = 0.0f;
        acc_a = acc_a + a00  * aw1;
        acc_a = acc_a + a10  * aw2;
        acc_a = acc_a + a01  * aw3;
        acc_a = acc_a + a11  * aw4;
        acc_a = acc_a + a00p * aw5;
        acc_a = acc_a + a10p * aw6;
        acc_a = acc_a + a01p * aw7;
        acc_a = acc_a + a11p * aw8;

        const float* lpb = sw + 516 + izb;
        float c00 = lpb[0*NV], c00p = lpb[0*NV+1];
        float c01 = lpb[1*NV], c01p = lpb[1*NV+1];
        float c10 = lpb[2*NV], c10p = lpb[2*NV+1];
        float c11 = lpb[3*NV], c11p = lpb[3*NV+1];
        float acc_b = 0.0f;
        acc_b = acc_b + c00  * bw1;
        acc_b = acc_b + c10  * bw2;
        acc_b = acc_b + c01  * bw3;
        acc_b = acc_b + c11  * bw4;
        acc_b = acc_b + c00p * bw5;
        acc_b = acc_b + c10p * bw6;
        acc_b = acc_b + c01p * bw7;
        acc_b = acc_b + c11p * bw8;

        v2f v;
        v.x = (acc_a > 0.5f) ? 1.0f : 0.0f;
        v.y = (acc_b > 0.5f) ? 1.0f : 0.0f;
        __builtin_nontemporal_store(v, (v2f*)(out_lab + obase) + l);
    }
}

extern "C" void kernel_launch(void* const* d_in, const int* in_sizes, int n_in,
                              void* d_out, int out_size, void* d_ws, size_t ws_size,
                              hipStream_t stream) {
    const float* in  = (const float*)d_in[0];
    const float* lab = (const float*)d_in[1];
    const float* T   = (const float*)d_in[2];
    float* out_in  = (float*)d_out;
    float* out_lab = (float*)d_out + TOTAL;

    // single kernel; one wave per output column; 8 columns per 512-thread block
    seg_aug_kernel<<<dim3(NWG), dim3(512), 0, stream>>>(
        in, lab, T, out_in, out_lab);
}

// Round 8
// 232.117 us; speedup vs baseline: 1.1387x; 1.0649x over previous
//
#include <hip/hip_runtime.h>

// SegmentationAugmentation: fused affine-grid + trilinear grid_sample (border,
// align_corners=False) for input (float out) and label (bool-as-float out).
//
// R11 = exact revert to R8, the measured best (bench 229.8us, kernel ~65us).
// Post-mortems that justify this as the terminal structure:
//  - R9 (persistent waves + LDS double-buffer): 66KB LDS halved occupancy
//    (78->35%) and regressed to 101us. TLP at 32 waves/CU IS the latency
//    hider; occupancy is sacred.
//  - R10 (bijective XCD-chunked swizzle): FETCH halved to 53.5MB (locality
//    worked) but the kernel REGRESSED to 88.6us -> HBM reads are not the
//    limiter; serving the gather from tiny hot per-XCD L2 bands raises
//    effective latency (same-line contention), occupancy dipped to 64%.
//  - R5 proved VALU is not binding (VALUBusy 70->41%, time flat).
//  - Bytes are minimal: FETCH 127.5MB = unique gather footprint, WRITE
//    134MB = output. Mixed 50/50 R/W at ~4.0 TB/s = ~63% of the 6.3TB/s
//    copy ceiling is the memory system's service rate for this pattern
//    (512B-granule scattered reads + streaming writes).
// Structure: one independent wave per output column, no barriers; paired-z
// (lane does z=2l,2l+1); global_load_lds DMA staging; split-vmcnt
// {inA,inB} / vmcnt(2) / {labA,labB} / vmcnt(1); nt stores; in-kernel xy/z
// math; 33KB LDS, low VGPR -> 4 blocks/CU = 32 waves/CU.
//
// Keeps the R4-R10-validated z-edge elimination: read s[iz0], s[iz0+1]
// directly; at iz0==127 fz==+0 so z1-plane weights are +0 and the one-past
// value (next row's z0 or a zeroed guard) contributes +-0 — bit-identical
// to the reference's +0*s[127] (absmax 0.0 across R4-R10).
//
// CORRECTNESS-CRITICAL: label output is a hard comparator (acc > 0.5) with
// voxels ~0.5 ulp from the boundary; all float math must stay bit-exact vs
// numpy: contract(off), x/y/z paths verbatim, w = (wz*wy)*wx, reference
// corner accumulation order (z outer, y mid, x inner).

#define NV 128
#define TOTAL (8 * NV * NV * NV)
#define WPB 8                 // waves (= columns) per block
#define WSTRIDE 1032          // floats per wave region: in 0..511, guard 512,
                              // lab 516..1027, guard 1028 (+pad, 16B-aligned)

typedef float v2f __attribute__((ext_vector_type(2)));

__global__ __launch_bounds__(512) void seg_aug_kernel(
    const float* __restrict__ in,
    const float* __restrict__ lab,
    const float* __restrict__ T,   // 16 floats, 4x4 row-major; rows 0..2 used
    float* __restrict__ out_in,
    float* __restrict__ out_lab)
{
#pragma clang fp contract(off)
    __shared__ __align__(16) float s[WPB * WSTRIDE];

    const int t = threadIdx.x;
    const int l = t & 63;                                   // lane
    const int w = __builtin_amdgcn_readfirstlane(t >> 6);   // wave id (uniform)
    const int col = (blockIdx.x << 3) | w;                  // global column
    const int o3 = col & (NV - 1);
    const int o2 = (col >> 7) & (NV - 1);
    const int b  = col >> 14;

    // ---- column-uniform x/y path (verbatim R3; T[i] are uniform s_loads) ----
    float p2 = (2.0f * (float)o2 + 1.0f) / 128.0f - 1.0f;
    float p3 = (2.0f * (float)o3 + 1.0f) / 128.0f - 1.0f;
    float ux = (T[0] * p2 + T[1] * p3) + T[3];
    float uy = (T[4] * p2 + T[5] * p3) + T[7];
    float gx = ((ux + 1.0f) * 128.0f - 1.0f) * 0.5f;
    float gy = ((uy + 1.0f) * 128.0f - 1.0f) * 0.5f;
    gx = fminf(fmaxf(gx, 0.0f), 127.0f);
    gy = fminf(fmaxf(gy, 0.0f), 127.0f);
    float fx0f = floorf(gx), fy0f = floorf(gy);
    float fx = gx - fx0f;
    float fy = gy - fy0f;
    const int ix0 = __builtin_amdgcn_readfirstlane((int)fx0f);
    const int iy0 = __builtin_amdgcn_readfirstlane((int)fy0f);
    const int ix1 = min(ix0 + 1, NV - 1);
    const int iy1 = min(iy0 + 1, NV - 1);
    const int r00 = (ix0 * NV + iy0) * NV;
    const int r01 = (ix0 * NV + iy1) * NV;
    const int r10 = (ix1 * NV + iy0) * NV;
    const int r11 = (ix1 * NV + iy1) * NV;

    // per-lane DMA sources: inst A = rows {00,01}, inst B = rows {10,11}
    // (when iy unclamped these are contiguous 1KB bursts)
    const int segoff = (l & 31) * 4;
    const int offA = ((l < 32) ? r00 : r01) + segoff;
    const int offB = ((l < 32) ? r10 : r11) + segoff;
    const size_t bbase = (size_t)b << 21;    // b * 128^3
    const float* ibp = in  + bbase;
    const float* lbp = lab + bbase;
    float* sw = &s[w * WSTRIDE];

    // ---- group 1 (oldest vmem ops): input DMAs ----
    __builtin_amdgcn_global_load_lds(ibp + offA, sw,       16, 0, 0);
    __builtin_amdgcn_global_load_lds(ibp + offB, sw + 256, 16, 0, 0);
    __builtin_amdgcn_sched_barrier(0);       // pin group order for vmcnt counting
    // ---- group 2: label DMAs ----
    __builtin_amdgcn_global_load_lds(lbp + offA, sw + 516, 16, 0, 0);
    __builtin_amdgcn_global_load_lds(lbp + offB, sw + 772, 16, 0, 0);

    if (l == 0) { sw[512] = 0.0f; sw[1028] = 0.0f; }   // finite one-past guards

    // ---- per-lane z path for z = 2l and 2l+1 (verbatim R3; overlaps DMA) ----
    float p4a = (2.0f * (float)(2 * l) + 1.0f) / 128.0f - 1.0f;
    float uza = T[10] * p4a + T[11];
    float gza = ((uza + 1.0f) * 128.0f - 1.0f) * 0.5f;
    gza = fminf(fmaxf(gza, 0.0f), 127.0f);
    float fz0a = floorf(gza);
    const int   iza = (int)fz0a;
    const float fza = gza - fz0a;

    float p4b = (2.0f * (float)(2 * l + 1) + 1.0f) / 128.0f - 1.0f;
    float uzb = T[10] * p4b + T[11];
    float gzb = ((uzb + 1.0f) * 128.0f - 1.0f) * 0.5f;
    gzb = fminf(fmaxf(gzb, 0.0f), 127.0f);
    float fz0b = floorf(gzb);
    const int   izb = (int)fz0b;
    const float fzb = gzb - fz0b;

    // ---- weights (VALU overlaps DMA latency) ----
    const float wx0 = 1.0f - fx, wx1 = fx;
    const float wy0 = 1.0f - fy, wy1 = fy;

    const float awz0 = 1.0f - fza, awz1 = fza;
    float atz0y0 = awz0 * wy0, atz0y1 = awz0 * wy1;
    float atz1y0 = awz1 * wy0, atz1y1 = awz1 * wy1;
    float aw1 = atz0y0 * wx0, aw2 = atz0y0 * wx1;
    float aw3 = atz0y1 * wx0, aw4 = atz0y1 * wx1;
    float aw5 = atz1y0 * wx0, aw6 = atz1y0 * wx1;
    float aw7 = atz1y1 * wx0, aw8 = atz1y1 * wx1;

    const float bwz0 = 1.0f - fzb, bwz1 = fzb;
    float btz0y0 = bwz0 * wy0, btz0y1 = bwz0 * wy1;
    float btz1y0 = bwz1 * wy0, btz1y1 = bwz1 * wy1;
    float bw1 = btz0y0 * wx0, bw2 = btz0y0 * wx1;
    float bw3 = btz0y1 * wx0, bw4 = btz0y1 * wx1;
    float bw5 = btz1y0 * wx0, bw6 = btz1y0 * wx1;
    float bw7 = btz1y1 * wx0, bw8 = btz1y1 * wx1;

    const int obase = col * NV;

    // ==== input half: needs only {inA, inB} -> vmcnt(2) ====
    asm volatile("s_waitcnt vmcnt(2)" ::: "memory");
    __builtin_amdgcn_sched_barrier(0);
    {
        const float* rpa = sw + iza;
        float a00 = rpa[0*NV], a00p = rpa[0*NV+1];
        float a01 = rpa[1*NV], a01p = rpa[1*NV+1];
        float a10 = rpa[2*NV], a10p = rpa[2*NV+1];
        float a11 = rpa[3*NV], a11p = rpa[3*NV+1];
        float acc_a = 0.0f;
        acc_a = acc_a + a00  * aw1;
        acc_a = acc_a + a10  * aw2;
        acc_a = acc_a + a01  * aw3;
        acc_a = acc_a + a11  * aw4;
        acc_a = acc_a + a00p * aw5;
        acc_a = acc_a + a10p * aw6;
        acc_a = acc_a + a01p * aw7;
        acc_a = acc_a + a11p * aw8;

        const float* rpb = sw + izb;
        float c00 = rpb[0*NV], c00p = rpb[0*NV+1];
        float c01 = rpb[1*NV], c01p = rpb[1*NV+1];
        float c10 = rpb[2*NV], c10p = rpb[2*NV+1];
        float c11 = rpb[3*NV], c11p = rpb[3*NV+1];
        float acc_b = 0.0f;
        acc_b = acc_b + c00  * bw1;
        acc_b = acc_b + c10  * bw2;
        acc_b = acc_b + c01  * bw3;
        acc_b = acc_b + c11  * bw4;
        acc_b = acc_b + c00p * bw5;
        acc_b = acc_b + c10p * bw6;
        acc_b = acc_b + c01p * bw7;
        acc_b = acc_b + c11p * bw8;

        v2f v; v.x = acc_a; v.y = acc_b;
        __builtin_nontemporal_store(v, (v2f*)(out_in + obase) + l);
    }

    // ==== label half: labs are the oldest remaining; the in-store is the
    // one allowed outstanding op -> vmcnt(1) ====
    asm volatile("s_waitcnt vmcnt(1)" ::: "memory");
    __builtin_amdgcn_sched_barrier(0);
    {
        const float* lpa = sw + 516 + iza;
        float a00 = lpa[0*NV], a00p = lpa[0*NV+1];
        float a01 = lpa[1*NV], a01p = lpa[1*NV+1];
        float a10 = lpa[2*NV], a10p = lpa[2*NV+1];
        float a11 = lpa[3*NV], a11p = lpa[3*NV+1];
        float acc_a = 0.0f;
        acc_a = acc_a + a00  * aw1;
        acc_a = acc_a + a10  * aw2;
        acc_a = acc_a + a01  * aw3;
        acc_a = acc_a + a11  * aw4;
        acc_a = acc_a + a00p * aw5;
        acc_a = acc_a + a10p * aw6;
        acc_a = acc_a + a01p * aw7;
        acc_a = acc_a + a11p * aw8;

        const float* lpb = sw + 516 + izb;
        float c00 = lpb[0*NV], c00p = lpb[0*NV+1];
        float c01 = lpb[1*NV], c01p = lpb[1*NV+1];
        float c10 = lpb[2*NV], c10p = lpb[2*NV+1];
        float c11 = lpb[3*NV], c11p = lpb[3*NV+1];
        float acc_b = 0.0f;
        acc_b = acc_b + c00  * bw1;
        acc_b = acc_b + c10  * bw2;
        acc_b = acc_b + c01  * bw3;
        acc_b = acc_b + c11  * bw4;
        acc_b = acc_b + c00p * bw5;
        acc_b = acc_b + c10p * bw6;
        acc_b = acc_b + c01p * bw7;
        acc_b = acc_b + c11p * bw8;

        v2f v;
        v.x = (acc_a > 0.5f) ? 1.0f : 0.0f;
        v.y = (acc_b > 0.5f) ? 1.0f : 0.0f;
        __builtin_nontemporal_store(v, (v2f*)(out_lab + obase) + l);
    }
}

extern "C" void kernel_launch(void* const* d_in, const int* in_sizes, int n_in,
                              void* d_out, int out_size, void* d_ws, size_t ws_size,
                              hipStream_t stream) {
    const float* in  = (const float*)d_in[0];
    const float* lab = (const float*)d_in[1];
    const float* T   = (const float*)d_in[2];
    float* out_in  = (float*)d_out;
    float* out_lab = (float*)d_out + TOTAL;

    // single kernel; one wave per output column; 8 columns per 512-thread block
    seg_aug_kernel<<<dim3(TOTAL / NV / WPB), dim3(512), 0, stream>>>(
        in, lab, T, out_in, out_lab);
}